// Round 12
// baseline (151.093 us; speedup 1.0000x reference)
//
#include <hip/hip_runtime.h>
#include <math.h>

#define BB 512
#define DD 512
#define CC 100000
#define CCPAD 100096          // 782 * 128
#define MARGIN 0.2f
#define CLIP_EPS 1e-8f
#define NCOLT 782             // class tiles of 128

typedef float f32x4  __attribute__((ext_vector_type(4)));
typedef long  lx2    __attribute__((ext_vector_type(2)));

// ---- workspace layout (byte offsets) ----
#define XN8_BYTES   262144u                       // fp8[512*512]
#define P_BYTES     1601536u                      // float[782*512]
#define PBASE       XN8_BYTES
#define AUX_OFF     (PBASE + 3u * P_BYTES)        // WN8 fp8[100096*512] = 51.2 MB

// ---- OCP e4m3fn encode with RNE (|a| <= 1 guaranteed by normalization) ----
__device__ inline unsigned f2e4m3(float a) {
    unsigned u = __builtin_bit_cast(unsigned, a);
    unsigned s = (u >> 24) & 0x80u;
    float ab = fabsf(a);
    unsigned code;
    if (ab >= 0.015625f) {   // normal: exp >= -6
        unsigned r = (u & 0x7FFFFFFFu) + 0x7FFFFu + ((u >> 20) & 1u);  // RNE @ 3 mant bits
        int e = (int)(r >> 23) - 127;
        unsigned m = (r >> 20) & 7u;
        code = (unsigned)((e + 7) << 3) | m;
    } else {                 // subnormal: value = n * 2^-9
        code = (unsigned)rintf(ab * 512.0f);
    }
    return s | code;
}

// K-interleaved storage: storage byte s in a 64-k block holds logical
// k = 32*((s>>3)&1) + 8*((s>>4)&3) + (s&7). One granule-aligned 16B read
// yields both mfma K-slices (bytes 0..7 -> slice0, 8..15 -> slice1).

// ---------------- kernel 1: normalize rows (W and X) -> fp8, K-interleaved ----------------
// blocks [0, CCPAD/4): 4 W rows each (zero-pad >= CC). blocks [CCPAD/4, +BB/4): 4 X rows.
__global__ __launch_bounds__(256) void k_prep(const float* __restrict__ w,
                                              const float* __restrict__ x,
                                              unsigned char* __restrict__ WN8,
                                              unsigned char* __restrict__ XN8,
                                              float* __restrict__ out) {
    int wv = threadIdx.x >> 6, lane = threadIdx.x & 63;
    int r = blockIdx.x * 4 + wv;
    const float* src;
    unsigned char* dst;
    bool zero = false;
    if (r < CCPAD) {
        zero = (r >= CC);
        src = w + (size_t)(zero ? 0 : r) * DD;
        dst = WN8 + (size_t)r * DD;
    } else {
        int xr = r - CCPAD;
        src = x + (size_t)xr * DD;
        dst = XN8 + (size_t)xr * DD;
    }
    // lane owns output bytes [8*lane, 8*lane+8) -> logical k K0..K0+7 (contiguous)
    int o  = lane * 8;
    int K0 = (o & ~63) + ((o >> 3) & 1) * 32 + ((o >> 4) & 3) * 8;
    float4 a = *(const float4*)(src + K0);
    float4 b = *(const float4*)(src + K0 + 4);
    if (zero) { a = make_float4(0.f,0.f,0.f,0.f); b = a; }
    float ss = a.x*a.x + a.y*a.y + a.z*a.z + a.w*a.w
             + b.x*b.x + b.y*b.y + b.z*b.z + b.w*b.w;
    for (int m = 1; m < 64; m <<= 1) ss += __shfl_xor(ss, m, 64);
    float inv = 1.0f / fmaxf(sqrtf(ss), 1e-12f);
    unsigned lo = f2e4m3(a.x*inv) | (f2e4m3(a.y*inv) << 8) | (f2e4m3(a.z*inv) << 16) | (f2e4m3(a.w*inv) << 24);
    unsigned hi = f2e4m3(b.x*inv) | (f2e4m3(b.y*inv) << 8) | (f2e4m3(b.z*inv) << 16) | (f2e4m3(b.w*inv) << 24);
    *(uint2*)(dst + o) = make_uint2(lo, hi);
    if (blockIdx.x == 0 && threadIdx.x == 0) out[0] = 0.0f;
}

// ------- kernel 2: LDS-FREE fp8 MFMA GEMM (global->reg fragments) + stats -------
// 1D grid 3128 (XCD-chunked). 4 waves (2x2), tile 128 classes x 128 batch.
// K=512 in 8 steps of BK=64. Both operands are L2/L3-resident, so fragments
// are loaded DIRECTLY global->reg: per instr, lanes {l,l+16,l+32,l+48} cover
// one row's full 64B K-block (16 x 64B lines). Register double-buffer, fully
// unrolled; compiler inserts counted vmcnt before consuming MFMAs. ZERO
// barriers / LDS / waitcnt in the main loop -- waves free-run.
__global__ __launch_bounds__(256) void k_gemmr(const unsigned char* __restrict__ WN8,
                                               const unsigned char* __restrict__ XN8,
                                               const float* __restrict__ rescale_p,
                                               float* __restrict__ ZP,
                                               float* __restrict__ S2P,
                                               float* __restrict__ S3P) {
    __shared__ float st[2][2][64][3];

    int h = blockIdx.x;
    int logical = (h & 7) * 391 + (h >> 3);   // 3128 = 8*391, bijective
    int ct = logical >> 2;                    // class tile 0..781
    int bt = logical & 3;                     // batch tile 0..3

    int tid = threadIdx.x;
    int lane = tid & 63, wid = tid >> 6;
    int wr = wid >> 1, wc = wid & 1;          // wr: class half, wc: batch half
    float rescale = rescale_p[0];

    // per-lane fragment base addresses (frag i adds i*16 rows; step kt adds kt*64 B)
    const unsigned char* wp = WN8 + (size_t)(ct * 128 + wr * 64 + (lane & 15)) * DD
                            + (lane >> 4) * 16;
    const unsigned char* xp = XN8 + (size_t)(bt * 128 + wc * 64 + (lane & 15)) * DD
                            + (lane >> 4) * 16;

    f32x4 acc[4][4];
#pragma unroll
    for (int i = 0; i < 4; i++)
#pragma unroll
        for (int j = 0; j < 4; j++) acc[i][j] = (f32x4){0.f, 0.f, 0.f, 0.f};

    lx2 a0[4], b0[4], a1[4], b1[4];
    auto LOADF = [&](lx2* A, lx2* B, int kt) {
#pragma unroll
        for (int i = 0; i < 4; ++i) {
            A[i] = *(const lx2*)(wp + (size_t)(i * 16) * DD + kt * 64);
            B[i] = *(const lx2*)(xp + (size_t)(i * 16) * DD + kt * 64);
        }
    };
    auto COMP = [&](const lx2* A, const lx2* B) {
#pragma unroll
        for (int i = 0; i < 4; i++)
#pragma unroll
            for (int j = 0; j < 4; j++)
                acc[i][j] = __builtin_amdgcn_mfma_f32_16x16x32_fp8_fp8(A[i][0], B[j][0], acc[i][j], 0, 0, 0);
#pragma unroll
        for (int i = 0; i < 4; i++)
#pragma unroll
            for (int j = 0; j < 4; j++)
                acc[i][j] = __builtin_amdgcn_mfma_f32_16x16x32_fp8_fp8(A[i][1], B[j][1], acc[i][j], 0, 0, 0);
    };

    // fully unrolled, register double-buffered, prefetch distance 2
    LOADF(a0, b0, 0);
    LOADF(a1, b1, 1);
    COMP(a0, b0); LOADF(a0, b0, 2);
    COMP(a1, b1); LOADF(a1, b1, 3);
    COMP(a0, b0); LOADF(a0, b0, 4);
    COMP(a1, b1); LOADF(a1, b1, 5);
    COMP(a0, b0); LOADF(a0, b0, 6);
    COMP(a1, b1); LOADF(a1, b1, 7);
    COMP(a0, b0);
    COMP(a1, b1);

    // ---- epilogue: cos -> clip -> exp stats (classes in-thread) ----
    float mref = fabsf(rescale);
    const float L2E = 1.44269504f;
    float rs = rescale * L2E, mb = mref * L2E;
    float zz[4] = {0.f,0.f,0.f,0.f}, q2[4] = {0.f,0.f,0.f,0.f}, q3[4] = {0.f,0.f,0.f,0.f};
#pragma unroll
    for (int mi = 0; mi < 4; mi++) {
#pragma unroll
        for (int reg = 0; reg < 4; reg++) {
            int c = ct * 128 + wr * 64 + mi * 16 + (lane >> 4) * 4 + reg;
            float mask = (c < CC) ? 1.0f : 0.0f;
#pragma unroll
            for (int ni = 0; ni < 4; ni++) {
                float cosv = acc[mi][ni][reg];
                cosv = fminf(fmaxf(cosv, -1.0f + CLIP_EPS), 1.0f - CLIP_EPS);
                float e = exp2f(fmaf(cosv, rs, -mb)) * mask;
                float e2 = e * e;
                zz[ni] += e;
                q2[ni] += e2;
                q3[ni] = fmaf(e2, e, q3[ni]);
            }
        }
    }
#pragma unroll
    for (int msk = 16; msk < 64; msk <<= 1) {
#pragma unroll
        for (int ni = 0; ni < 4; ni++) {
            zz[ni] += __shfl_xor(zz[ni], msk, 64);
            q2[ni] += __shfl_xor(q2[ni], msk, 64);
            q3[ni] += __shfl_xor(q3[ni], msk, 64);
        }
    }
    if (lane < 16) {
#pragma unroll
        for (int ni = 0; ni < 4; ni++) {
            st[wc][wr][ni * 16 + lane][0] = zz[ni];
            st[wc][wr][ni * 16 + lane][1] = q2[ni];
            st[wc][wr][ni * 16 + lane][2] = q3[ni];
        }
    }
    __syncthreads();
    if (tid < 128) {
        int bh = tid >> 6, bl = tid & 63;
        float Z  = st[bh][0][bl][0] + st[bh][1][bl][0];
        float S2 = st[bh][0][bl][1] + st[bh][1][bl][1];
        float S3 = st[bh][0][bl][2] + st[bh][1][bl][2];
        size_t gi = (size_t)ct * BB + bt * 128 + tid;
        ZP[gi] = Z; S2P[gi] = S2; S3P[gi] = S3;
    }
}

// ---------------- kernel 3: combine partials, margin fixup, loss ----------------
__global__ __launch_bounds__(256) void k_final(const float* __restrict__ x,
                                               const float* __restrict__ w,
                                               const int* __restrict__ y,
                                               const float* __restrict__ rescale_p,
                                               const float* __restrict__ ZP,
                                               const float* __restrict__ S2P,
                                               const float* __restrict__ S3P,
                                               float* __restrict__ out) {
    int b = blockIdx.x, tid = threadIdx.x;
    int yb = y[b];

    float dq = 0.f, qx = 0.f, qw = 0.f;
#pragma unroll
    for (int i = 0; i < 2; i++) {
        int idx = tid + i * 256;
        float xv = x[b * DD + idx];
        float wv = w[(size_t)yb * DD + idx];
        dq = fmaf(xv, wv, dq);
        qx = fmaf(xv, xv, qx);
        qw = fmaf(wv, wv, qw);
    }
    for (int m = 1; m < 64; m <<= 1) {
        dq += __shfl_xor(dq, m, 64);
        qx += __shfl_xor(qx, m, 64);
        qw += __shfl_xor(qw, m, 64);
    }
    __shared__ float sd[4], sx[4], sw[4], szs[4], s2s[4], s3s[4];
    int wid = tid >> 6, lane = tid & 63;
    if (lane == 0) { sd[wid] = dq; sx[wid] = qx; sw[wid] = qw; }

    float rz = 0.f, r2 = 0.f, r3 = 0.f;
    for (int ch = tid; ch < NCOLT; ch += 256) {
        size_t gi = (size_t)ch * BB + b;
        rz += ZP[gi]; r2 += S2P[gi]; r3 += S3P[gi];
    }
    for (int m = 1; m < 64; m <<= 1) {
        rz += __shfl_xor(rz, m, 64);
        r2 += __shfl_xor(r2, m, 64);
        r3 += __shfl_xor(r3, m, 64);
    }
    if (lane == 0) { szs[wid] = rz; s2s[wid] = r2; s3s[wid] = r3; }
    __syncthreads();

    if (tid == 0) {
        float Z  = szs[0] + szs[1] + szs[2] + szs[3];
        float S2 = s2s[0] + s2s[1] + s2s[2] + s2s[3];
        float S3 = s3s[0] + s3s[1] + s3s[2] + s3s[3];
        float dot = sd[0] + sd[1] + sd[2] + sd[3];
        float ssx = sx[0] + sx[1] + sx[2] + sx[3];
        float ssw = sw[0] + sw[1] + sw[2] + sw[3];
        float rescale = rescale_p[0];
        float mref = fabsf(rescale);
        float fc = dot / (fmaxf(sqrtf(ssx), 1e-12f) * fmaxf(sqrtf(ssw), 1e-12f));
        fc = fminf(fmaxf(fc, -1.0f + CLIP_EPS), 1.0f - CLIP_EPS);
        float su = rescale * fc;
        float fcm = fc * cosf(MARGIN) - sqrtf(fmaxf(1.0f - fc * fc, 0.0f)) * sinf(MARGIN);
        float smv = rescale * fcm;
        float eU = __expf(su - mref), eM = __expf(smv - mref);
        Z  += eM - eU;
        S2 += eM * eM - eU * eU;
        S3 += eM * eM * eM - eU * eU * eU;
        float py = eM / Z;
        // sum_c exp(p_c) = C + 1 + S2/(2Z^2) + S3/(6Z^3) (remainder < 1e-13)
        float sumexp = (float)CC + 1.0f + S2 / (2.0f * Z * Z) + S3 / (6.0f * Z * Z * Z);
        float nll = logf(sumexp) - py;
        atomicAdd(out, nll * (1.0f / (float)BB));
    }
}

extern "C" void kernel_launch(void* const* d_in, const int* in_sizes, int n_in,
                              void* d_out, int out_size, void* d_ws, size_t ws_size,
                              hipStream_t stream) {
    const float* x       = (const float*)d_in[0];
    const int*   y       = (const int*)  d_in[1];
    const float* w       = (const float*)d_in[2];
    const float* rescale = (const float*)d_in[3];
    float* out = (float*)d_out;
    char*  wsb = (char*)d_ws;

    unsigned char* XN8 = (unsigned char*)(wsb);
    float* ZP  = (float*)(wsb + PBASE);
    float* S2P = (float*)(wsb + PBASE + P_BYTES);
    float* S3P = (float*)(wsb + PBASE + 2u * P_BYTES);
    unsigned char* WN8 = (unsigned char*)(wsb + AUX_OFF);

    k_prep  <<<dim3(CCPAD / 4 + BB / 4), dim3(256), 0, stream>>>(w, x, WN8, XN8, out);
    k_gemmr <<<dim3(8 * 391), dim3(256), 0, stream>>>(WN8, XN8, rescale, ZP, S2P, S3P);
    k_final <<<dim3(BB), dim3(256), 0, stream>>>(x, w, y, rescale, ZP, S2P, S3P, out);
}

// Round 13
// 105.590 us; speedup vs baseline: 1.4309x; 1.4309x over previous
//
#include <hip/hip_runtime.h>
#include <math.h>

#define BB 512
#define DD 512
#define CC 100000
#define CCPAD 100096          // 782 * 128
#define MARGIN 0.2f
#define CLIP_EPS 1e-8f
#define NCOLT 782             // class tiles of 128

typedef float f32x4  __attribute__((ext_vector_type(4)));
typedef long  lx2    __attribute__((ext_vector_type(2)));

// ---- workspace layout (byte offsets) ----
#define XN8_BYTES   262144u                       // fp8[512*512]
#define P_BYTES     1601536u                      // float[782*512]
#define PBASE       XN8_BYTES
#define AUX_OFF     (PBASE + 3u * P_BYTES)        // WN8 fp8[100096*512] = 51.2 MB

// ---- OCP e4m3fn encode with RNE (|a| <= 1 guaranteed by normalization) ----
__device__ inline unsigned f2e4m3(float a) {
    unsigned u = __builtin_bit_cast(unsigned, a);
    unsigned s = (u >> 24) & 0x80u;
    float ab = fabsf(a);
    unsigned code;
    if (ab >= 0.015625f) {   // normal: exp >= -6
        unsigned r = (u & 0x7FFFFFFFu) + 0x7FFFFu + ((u >> 20) & 1u);  // RNE @ 3 mant bits
        int e = (int)(r >> 23) - 127;
        unsigned m = (r >> 20) & 7u;
        code = (unsigned)((e + 7) << 3) | m;
    } else {                 // subnormal: value = n * 2^-9
        code = (unsigned)rintf(ab * 512.0f);
    }
    return s | code;
}

// swizzled byte offset within a [rows][64 B] fp8 tile; b = byte-in-row
// (16B-granule XOR involution; gload_lds-compatible; b128 reads bank-uniform)
__device__ inline int soff8(int row, int b) {
    return row * 64 + ((((b >> 4) ^ ((row >> 1) & 3)) << 4)) + (b & 15);
}

// K-interleaved storage: storage byte s in a 64-k block holds logical
// k = 32*((s>>3)&1) + 8*((s>>4)&3) + (s&7). One granule-aligned 16B read
// yields both mfma K-slices (bytes 0..7 -> slice0, 8..15 -> slice1).

// ---------------- kernel 1: normalize rows (W and X) -> fp8, K-interleaved ----------------
// blocks [0, CCPAD/4): 4 W rows each (zero-pad >= CC). blocks [CCPAD/4, +BB/4): 4 X rows.
__global__ __launch_bounds__(256) void k_prep(const float* __restrict__ w,
                                              const float* __restrict__ x,
                                              unsigned char* __restrict__ WN8,
                                              unsigned char* __restrict__ XN8,
                                              float* __restrict__ out) {
    int wv = threadIdx.x >> 6, lane = threadIdx.x & 63;
    int r = blockIdx.x * 4 + wv;
    const float* src;
    unsigned char* dst;
    bool zero = false;
    if (r < CCPAD) {
        zero = (r >= CC);
        src = w + (size_t)(zero ? 0 : r) * DD;
        dst = WN8 + (size_t)r * DD;
    } else {
        int xr = r - CCPAD;
        src = x + (size_t)xr * DD;
        dst = XN8 + (size_t)xr * DD;
    }
    // lane owns output bytes [8*lane, 8*lane+8) -> logical k K0..K0+7 (contiguous)
    int o  = lane * 8;
    int K0 = (o & ~63) + ((o >> 3) & 1) * 32 + ((o >> 4) & 3) * 8;
    float4 a = *(const float4*)(src + K0);
    float4 b = *(const float4*)(src + K0 + 4);
    if (zero) { a = make_float4(0.f,0.f,0.f,0.f); b = a; }
    float ss = a.x*a.x + a.y*a.y + a.z*a.z + a.w*a.w
             + b.x*b.x + b.y*b.y + b.z*b.z + b.w*b.w;
    for (int m = 1; m < 64; m <<= 1) ss += __shfl_xor(ss, m, 64);
    float inv = 1.0f / fmaxf(sqrtf(ss), 1e-12f);
    unsigned lo = f2e4m3(a.x*inv) | (f2e4m3(a.y*inv) << 8) | (f2e4m3(a.z*inv) << 16) | (f2e4m3(a.w*inv) << 24);
    unsigned hi = f2e4m3(b.x*inv) | (f2e4m3(b.y*inv) << 8) | (f2e4m3(b.z*inv) << 16) | (f2e4m3(b.w*inv) << 24);
    *(uint2*)(dst + o) = make_uint2(lo, hi);
    if (blockIdx.x == 0 && threadIdx.x == 0) out[0] = 0.0f;
}

// ------- kernel 2: fp8 triple-buffered counted-vmcnt MFMA + fused stats -------
// 1D grid 3128 (XCD-chunked). 4 waves (2x2), tile 128 classes x 128 batch.
// K=512 in 8 steps of BK=64. Three LDS buffers, prefetch distance 3,
// s_barrier + literal vmcnt(8/4/0) -- verified schedule (4 loads/stage).
// K-interleaved layout -> 8 ds_read_b128 per wave-step.
__global__ __launch_bounds__(256) void k_gemm8(const unsigned char* __restrict__ WN8,
                                               const unsigned char* __restrict__ XN8,
                                               const float* __restrict__ rescale_p,
                                               float* __restrict__ ZP,
                                               float* __restrict__ S2P,
                                               float* __restrict__ S3P) {
    __shared__ __align__(16) unsigned char Wt[3][128 * 64];
    __shared__ __align__(16) unsigned char Xs[3][128 * 64];
    __shared__ float st[2][2][64][3];   // [batch half][class half][batch row][stat]

    int h = blockIdx.x;
    int logical = (h & 7) * 391 + (h >> 3);   // 3128 = 8*391, bijective
    int ct = logical >> 2;                    // class tile 0..781
    int bt = logical & 3;                     // batch tile 0..3

    int tid = threadIdx.x;
    int lane = tid & 63, wid = tid >> 6;
    int wr = wid >> 1, wc = wid & 1;          // wr: class half, wc: batch half
    float rescale = rescale_p[0];

    // staging: chunk ch = i*256 + wid*64 + lane ; row = ch>>2 ; granule j = ch&3
    // LDS linear for gload_lds; SOURCE granule is inverse-swizzled (involution).
    int rl0 = wid * 16 + (lane >> 2);
    int j0  = lane & 3;
    const unsigned char* wbase = WN8 + (size_t)(ct * 128) * DD;
    const unsigned char* xbase = XN8 + (size_t)(bt * 128) * DD;

    auto STAGE = [&](int b, int kt) {
#pragma unroll
        for (int i = 0; i < 2; ++i) {
            int rl = i * 64 + rl0;
            int jsrc = j0 ^ ((rl >> 1) & 3);
            const unsigned char* ws_ = wbase + (size_t)rl * DD + kt * 64 + jsrc * 16;
            const unsigned char* xs_ = xbase + (size_t)rl * DD + kt * 64 + jsrc * 16;
            unsigned char* wd = &Wt[b][(i * 256 + wid * 64) * 16];
            unsigned char* xd = &Xs[b][(i * 256 + wid * 64) * 16];
            __builtin_amdgcn_global_load_lds(
                (const __attribute__((address_space(1))) void*)ws_,
                (__attribute__((address_space(3))) void*)wd, 16, 0, 0);
            __builtin_amdgcn_global_load_lds(
                (const __attribute__((address_space(1))) void*)xs_,
                (__attribute__((address_space(3))) void*)xd, 16, 0, 0);
        }
    };

    // fragment byte offsets: granule-aligned b128, one per frag row (both slices)
    int roA[4], roB[4];
#pragma unroll
    for (int i = 0; i < 4; ++i) {
        int kb = (lane >> 4) * 16;
        roA[i] = soff8(wr * 64 + i * 16 + (lane & 15), kb);
        roB[i] = soff8(wc * 64 + i * 16 + (lane & 15), kb);
    }

    f32x4 acc[4][4];
#pragma unroll
    for (int i = 0; i < 4; i++)
#pragma unroll
        for (int j = 0; j < 4; j++) acc[i][j] = (f32x4){0.f, 0.f, 0.f, 0.f};

    auto COMPUTE = [&](int b) {
        lx2 a[4], bb[4];
#pragma unroll
        for (int i = 0; i < 4; i++) a[i]  = *(const lx2*)&Wt[b][roA[i]];
#pragma unroll
        for (int i = 0; i < 4; i++) bb[i] = *(const lx2*)&Xs[b][roB[i]];
#pragma unroll
        for (int i = 0; i < 4; i++)
#pragma unroll
            for (int j = 0; j < 4; j++)
                acc[i][j] = __builtin_amdgcn_mfma_f32_16x16x32_fp8_fp8(a[i][0], bb[j][0], acc[i][j], 0, 0, 0);
#pragma unroll
        for (int i = 0; i < 4; i++)
#pragma unroll
            for (int j = 0; j < 4; j++)
                acc[i][j] = __builtin_amdgcn_mfma_f32_16x16x32_fp8_fp8(a[i][1], bb[j][1], acc[i][j], 0, 0, 0);
    };

    // ---- prologue: fill 3 buffers, wait only for buf0 (8 newer stay in flight) ----
    STAGE(0, 0);
    STAGE(1, 1);
    STAGE(2, 2);
    asm volatile("s_waitcnt vmcnt(8)" ::: "memory");
    __builtin_amdgcn_s_barrier();

    // ---- main loop: counted vmcnt, no full drain ----
    int cur = 0;
    for (int kt = 0; kt < 8; ++kt) {
        COMPUTE(cur);
        if (kt == 7) break;
        __builtin_amdgcn_s_barrier();      // all waves done reading buf `cur`
        if (kt < 5) {
            STAGE(cur, kt + 3);            // restage just-freed buffer
            asm volatile("s_waitcnt vmcnt(8)" ::: "memory");   // tile kt+1 arrived
        } else if (kt == 5) {
            asm volatile("s_waitcnt vmcnt(4)" ::: "memory");
        } else {
            asm volatile("s_waitcnt vmcnt(0)" ::: "memory");
        }
        __builtin_amdgcn_s_barrier();      // all waves' kt+1 data present
        cur = (cur == 2) ? 0 : cur + 1;
    }

    // ---- epilogue: cos -> clip -> exp stats (classes in-thread) ----
    float mref = fabsf(rescale);
    const float L2E = 1.44269504f;
    float rs = rescale * L2E, mb = mref * L2E;
    float zz[4] = {0.f,0.f,0.f,0.f}, q2[4] = {0.f,0.f,0.f,0.f}, q3[4] = {0.f,0.f,0.f,0.f};
#pragma unroll
    for (int mi = 0; mi < 4; mi++) {
#pragma unroll
        for (int reg = 0; reg < 4; reg++) {
            int c = ct * 128 + wr * 64 + mi * 16 + (lane >> 4) * 4 + reg;
            float mask = (c < CC) ? 1.0f : 0.0f;
#pragma unroll
            for (int ni = 0; ni < 4; ni++) {
                float cosv = acc[mi][ni][reg];
                cosv = fminf(fmaxf(cosv, -1.0f + CLIP_EPS), 1.0f - CLIP_EPS);
                float e = exp2f(fmaf(cosv, rs, -mb)) * mask;
                float e2 = e * e;
                zz[ni] += e;
                q2[ni] += e2;
                q3[ni] = fmaf(e2, e, q3[ni]);
            }
        }
    }
#pragma unroll
    for (int msk = 16; msk < 64; msk <<= 1) {
#pragma unroll
        for (int ni = 0; ni < 4; ni++) {
            zz[ni] += __shfl_xor(zz[ni], msk, 64);
            q2[ni] += __shfl_xor(q2[ni], msk, 64);
            q3[ni] += __shfl_xor(q3[ni], msk, 64);
        }
    }
    if (lane < 16) {
#pragma unroll
        for (int ni = 0; ni < 4; ni++) {
            st[wc][wr][ni * 16 + lane][0] = zz[ni];
            st[wc][wr][ni * 16 + lane][1] = q2[ni];
            st[wc][wr][ni * 16 + lane][2] = q3[ni];
        }
    }
    __syncthreads();
    if (tid < 128) {
        int bh = tid >> 6, bl = tid & 63;
        float Z  = st[bh][0][bl][0] + st[bh][1][bl][0];
        float S2 = st[bh][0][bl][1] + st[bh][1][bl][1];
        float S3 = st[bh][0][bl][2] + st[bh][1][bl][2];
        size_t gi = (size_t)ct * BB + bt * 128 + tid;
        ZP[gi] = Z; S2P[gi] = S2; S3P[gi] = S3;
    }
}

// ---------------- kernel 3: combine partials, margin fixup, loss ----------------
__global__ __launch_bounds__(256) void k_final(const float* __restrict__ x,
                                               const float* __restrict__ w,
                                               const int* __restrict__ y,
                                               const float* __restrict__ rescale_p,
                                               const float* __restrict__ ZP,
                                               const float* __restrict__ S2P,
                                               const float* __restrict__ S3P,
                                               float* __restrict__ out) {
    int b = blockIdx.x, tid = threadIdx.x;
    int yb = y[b];

    // dot(x_b, w_yb), ||x_b||^2, ||w_yb||^2 in f32
    float dq = 0.f, qx = 0.f, qw = 0.f;
#pragma unroll
    for (int i = 0; i < 2; i++) {
        int idx = tid + i * 256;
        float xv = x[b * DD + idx];
        float wv = w[(size_t)yb * DD + idx];
        dq = fmaf(xv, wv, dq);
        qx = fmaf(xv, xv, qx);
        qw = fmaf(wv, wv, qw);
    }
    for (int m = 1; m < 64; m <<= 1) {
        dq += __shfl_xor(dq, m, 64);
        qx += __shfl_xor(qx, m, 64);
        qw += __shfl_xor(qw, m, 64);
    }
    __shared__ float sd[4], sx[4], sw[4], szs[4], s2s[4], s3s[4];
    int wid = tid >> 6, lane = tid & 63;
    if (lane == 0) { sd[wid] = dq; sx[wid] = qx; sw[wid] = qw; }

    float rz = 0.f, r2 = 0.f, r3 = 0.f;
    for (int ch = tid; ch < NCOLT; ch += 256) {
        size_t gi = (size_t)ch * BB + b;
        rz += ZP[gi]; r2 += S2P[gi]; r3 += S3P[gi];
    }
    for (int m = 1; m < 64; m <<= 1) {
        rz += __shfl_xor(rz, m, 64);
        r2 += __shfl_xor(r2, m, 64);
        r3 += __shfl_xor(r3, m, 64);
    }
    if (lane == 0) { szs[wid] = rz; s2s[wid] = r2; s3s[wid] = r3; }
    __syncthreads();

    if (tid == 0) {
        float Z  = szs[0] + szs[1] + szs[2] + szs[3];
        float S2 = s2s[0] + s2s[1] + s2s[2] + s2s[3];
        float S3 = s3s[0] + s3s[1] + s3s[2] + s3s[3];
        float dot = sd[0] + sd[1] + sd[2] + sd[3];
        float ssx = sx[0] + sx[1] + sx[2] + sx[3];
        float ssw = sw[0] + sw[1] + sw[2] + sw[3];
        float rescale = rescale_p[0];
        float mref = fabsf(rescale);
        float fc = dot / (fmaxf(sqrtf(ssx), 1e-12f) * fmaxf(sqrtf(ssw), 1e-12f));
        fc = fminf(fmaxf(fc, -1.0f + CLIP_EPS), 1.0f - CLIP_EPS);
        float su = rescale * fc;
        float fcm = fc * cosf(MARGIN) - sqrtf(fmaxf(1.0f - fc * fc, 0.0f)) * sinf(MARGIN);
        float smv = rescale * fcm;
        float eU = __expf(su - mref), eM = __expf(smv - mref);
        Z  += eM - eU;
        S2 += eM * eM - eU * eU;
        S3 += eM * eM * eM - eU * eU * eU;
        float py = eM / Z;
        // sum_c exp(p_c) = C + 1 + S2/(2Z^2) + S3/(6Z^3) (remainder < 1e-13)
        float sumexp = (float)CC + 1.0f + S2 / (2.0f * Z * Z) + S3 / (6.0f * Z * Z * Z);
        float nll = logf(sumexp) - py;
        atomicAdd(out, nll * (1.0f / (float)BB));
    }
}

extern "C" void kernel_launch(void* const* d_in, const int* in_sizes, int n_in,
                              void* d_out, int out_size, void* d_ws, size_t ws_size,
                              hipStream_t stream) {
    const float* x       = (const float*)d_in[0];
    const int*   y       = (const int*)  d_in[1];
    const float* w       = (const float*)d_in[2];
    const float* rescale = (const float*)d_in[3];
    float* out = (float*)d_out;
    char*  wsb = (char*)d_ws;

    unsigned char* XN8 = (unsigned char*)(wsb);
    float* ZP  = (float*)(wsb + PBASE);
    float* S2P = (float*)(wsb + PBASE + P_BYTES);
    float* S3P = (float*)(wsb + PBASE + 2u * P_BYTES);
    unsigned char* WN8 = (unsigned char*)(wsb + AUX_OFF);

    k_prep  <<<dim3(CCPAD / 4 + BB / 4), dim3(256), 0, stream>>>(w, x, WN8, XN8, out);
    k_gemm8 <<<dim3(8 * 391), dim3(256), 0, stream>>>(WN8, XN8, rescale, ZP, S2P, S3P);
    k_final <<<dim3(BB), dim3(256), 0, stream>>>(x, w, y, rescale, ZP, S2P, S3P, out);
}